// Round 8
// baseline (205.005 us; speedup 1.0000x reference)
//
#include <hip/hip_runtime.h>

#define NN 50000
#define NE 600000
#define NG 64
#define SCAN_T 1024
#define SCAN_NB ((NN + SCAN_T - 1) / SCAN_T)  // 49
#define PSPLIT 16

typedef unsigned int uint_t;
typedef unsigned short ushort_t;

__device__ __forceinline__ ushort_t f2bf(float x) {
    uint_t u = __builtin_bit_cast(uint_t, x);
    u = (u + 0x7FFFu + ((u >> 16) & 1u)) >> 16;  // round-to-nearest-even
    return (ushort_t)u;
}
__device__ __forceinline__ float bf_lo(uint_t p) {
    uint_t v = p << 16; return __builtin_bit_cast(float, v);
}
__device__ __forceinline__ float bf_hi(uint_t p) {
    uint_t v = p & 0xFFFF0000u; return __builtin_bit_cast(float, v);
}

// ---------------- degree histogram (int) ----------------
__global__ void k_zero_deg(int* __restrict__ deg) {
    int i = blockIdx.x * blockDim.x + threadIdx.x;
    if (i < NN) deg[i] = 0;
}

__global__ void k_hist(const int* __restrict__ dst, int* __restrict__ deg) {
    int e = blockIdx.x * blockDim.x + threadIdx.x;
    if (e < NE) atomicAdd(&deg[dst[e]], 1);
}

// ---------------- 3-level parallel exclusive scan ----------------
__global__ __launch_bounds__(SCAN_T) void k_scan1(const int* __restrict__ deg,
                                                  int* __restrict__ blockSums) {
    __shared__ int s[SCAN_T];
    int i = blockIdx.x * SCAN_T + threadIdx.x;
    s[threadIdx.x] = (i < NN) ? deg[i] : 0;
    __syncthreads();
    for (int off = SCAN_T / 2; off > 0; off >>= 1) {
        if (threadIdx.x < off) s[threadIdx.x] += s[threadIdx.x + off];
        __syncthreads();
    }
    if (threadIdx.x == 0) blockSums[blockIdx.x] = s[0];
}

__global__ void k_scan2(const int* __restrict__ blockSums, int* __restrict__ blockOffs) {
    int t = threadIdx.x;  // one wave (64 lanes), SCAN_NB=49 <= 64
    int orig = (t < SCAN_NB) ? blockSums[t] : 0;
    int v = orig;
    for (int off = 1; off < 64; off <<= 1) {
        int u = __shfl_up(v, off);
        if (t >= off) v += u;
    }
    if (t < SCAN_NB) blockOffs[t] = v - orig;  // exclusive
}

__global__ __launch_bounds__(SCAN_T) void k_scan3(const int* __restrict__ deg,
                                                  const int* __restrict__ blockOffs,
                                                  int* __restrict__ rowptr,
                                                  int* __restrict__ cursor,
                                                  float* __restrict__ dinv) {
    __shared__ int s[SCAN_T];
    const int t = threadIdx.x;
    const int i = blockIdx.x * SCAN_T + t;
    const int v = (i < NN) ? deg[i] : 0;
    s[t] = v;
    __syncthreads();
    for (int off = 1; off < SCAN_T; off <<= 1) {
        int u = (t >= off) ? s[t - off] : 0;
        int cur = s[t];
        __syncthreads();
        s[t] = cur + u;
        __syncthreads();
    }
    if (i < NN) {
        int ex = blockOffs[blockIdx.x] + s[t] - v;  // exclusive prefix
        rowptr[i] = ex;
        cursor[i] = ex;
        dinv[i] = rsqrtf((float)(v + 1));
    }
    if (i == 0) rowptr[NN] = NE;  // every edge's dst is in-range
}

// ---------------- scatter edges into CSR buckets ----------------
__global__ void k_scatter(const int* __restrict__ src, const int* __restrict__ dst,
                          int* __restrict__ cursor, int* __restrict__ csr_src) {
    int e = blockIdx.x * blockDim.x + threadIdx.x;
    if (e >= NE) return;
    int d = dst[e];
    int p = atomicAdd(&cursor[d], 1);
    csr_src[p] = src[e];
}

// ---------------- LDS-resident GEMM: Hb = bf16((X @ W) * dinv) ----------------
// Block covers BM=64 rows x full COUT. X tile AND W both in LDS (W in KPH-row
// phases of 16KB). Inner loop is pure LDS+FMA.
//   gemm1: COUT=128 -> TPC=32, NGRP=8,  RPT=8, KPH=32
//   gemm2: COUT=64  -> TPC=16, NGRP=16, RPT=4, KPH=64
template <int CIN, int COUT, int KPH>
__global__ __launch_bounds__(256) void k_gemm(const float* __restrict__ X,
                                              const float* __restrict__ W,
                                              const float* __restrict__ dinv,
                                              ushort_t* __restrict__ Hb) {
    constexpr int TPC = COUT / 4;       // col-threads
    constexpr int NGRP = 256 / TPC;     // row groups
    constexpr int BM = 64;
    constexpr int RPT = BM / NGRP;      // rows per thread
    constexpr int LDW = CIN + 4;        // pad: 4-bank shift per row
    constexpr int F4R = CIN / 4;
    constexpr int WF4 = COUT / 4;
    __shared__ float xs[BM][LDW];
    __shared__ float wsh[KPH][COUT];
    const int tid = threadIdx.x;
    const int row0 = blockIdx.x * BM;

    // stage X tile (coalesced float4)
    for (int idx = tid; idx < BM * F4R; idx += 256) {
        int r = idx / F4R, c4 = idx % F4R;
        int row = row0 + r;
        float4 v = make_float4(0.f, 0.f, 0.f, 0.f);
        if (row < NN) v = ((const float4*)X)[(long)row * F4R + c4];
        *(float4*)&xs[r][c4 * 4] = v;
    }

    const int g = tid / TPC;             // row group
    const int j = (tid % TPC) * 4;       // col
    const int r0 = g * RPT;

    float4 acc[RPT];
#pragma unroll
    for (int r = 0; r < RPT; ++r) acc[r] = make_float4(0.f, 0.f, 0.f, 0.f);

    for (int ph = 0; ph < CIN / KPH; ++ph) {
        __syncthreads();  // prev-phase compute done (and X stage on ph=0)
        for (int idx = tid; idx < KPH * WF4; idx += 256) {
            int kk = idx / WF4, c4 = idx % WF4;
            *(float4*)&wsh[kk][c4 * 4] =
                *(const float4*)&W[(long)(ph * KPH + kk) * COUT + c4 * 4];
        }
        __syncthreads();

        for (int kk = 0; kk < KPH; kk += 4) {
            const int k = ph * KPH + kk;
            const float4 w0 = *(const float4*)&wsh[kk + 0][j];
            const float4 w1 = *(const float4*)&wsh[kk + 1][j];
            const float4 w2 = *(const float4*)&wsh[kk + 2][j];
            const float4 w3 = *(const float4*)&wsh[kk + 3][j];
#pragma unroll
            for (int r = 0; r < RPT; ++r) {
                const float4 xv = *(const float4*)&xs[r0 + r][k];
                acc[r].x += xv.x * w0.x + xv.y * w1.x + xv.z * w2.x + xv.w * w3.x;
                acc[r].y += xv.x * w0.y + xv.y * w1.y + xv.z * w2.y + xv.w * w3.y;
                acc[r].z += xv.x * w0.z + xv.y * w1.z + xv.z * w2.z + xv.w * w3.z;
                acc[r].w += xv.x * w0.w + xv.y * w1.w + xv.z * w2.w + xv.w * w3.w;
            }
        }
    }

#pragma unroll
    for (int r = 0; r < RPT; ++r) {
        int row = row0 + r0 + r;
        if (row < NN) {
            float sc = dinv[row];
            ushort4 o;
            o.x = f2bf(acc[r].x * sc);
            o.y = f2bf(acc[r].y * sc);
            o.z = f2bf(acc[r].z * sc);
            o.w = f2bf(acc[r].w * sc);
            *(ushort4*)&Hb[(long)row * COUT + j] = o;
        }
    }
}

// ---------------- gather aggregation on pre-scaled bf16 Hb ----------------
// OUT[d] = dd * (Hb[d] + sum_in Hb[s])  [+bias, relu]   (f32 accumulate)
template <int C, bool BIAS_RELU>
__global__ __launch_bounds__(256) void k_agg(const int* __restrict__ rowptr,
                                             const int* __restrict__ csr_src,
                                             const float* __restrict__ dinv,
                                             const ushort_t* __restrict__ Hb,
                                             const float* __restrict__ bias,
                                             float* __restrict__ OUT) {
    constexpr int TPN = C / 8;        // threads per node (uint4 = 8 bf16 channels)
    constexpr int NPB = 256 / TPN;    // nodes per block
    const int node = blockIdx.x * NPB + threadIdx.x / TPN;
    if (node >= NN) return;
    const int lane = threadIdx.x % TPN;
    const float dd = dinv[node];
    const uint4* __restrict__ H4 = (const uint4*)Hb;

    float a0, a1, a2, a3, a4, a5, a6, a7;
    {
        uint4 sv = H4[(long)node * TPN + lane];  // self term (pre-scaled)
        a0 = bf_lo(sv.x); a1 = bf_hi(sv.x);
        a2 = bf_lo(sv.y); a3 = bf_hi(sv.y);
        a4 = bf_lo(sv.z); a5 = bf_hi(sv.z);
        a6 = bf_lo(sv.w); a7 = bf_hi(sv.w);
    }

    const int beg = rowptr[node], end = rowptr[node + 1];
    int k = beg;
    const int n4 = beg + ((end - beg) & ~3);
    for (; k < n4; k += 4) {
        int s0 = csr_src[k + 0];
        int s1 = csr_src[k + 1];
        int s2 = csr_src[k + 2];
        int s3 = csr_src[k + 3];
        uint4 h0 = H4[(long)s0 * TPN + lane];
        uint4 h1 = H4[(long)s1 * TPN + lane];
        uint4 h2 = H4[(long)s2 * TPN + lane];
        uint4 h3 = H4[(long)s3 * TPN + lane];
        a0 += (bf_lo(h0.x) + bf_lo(h1.x)) + (bf_lo(h2.x) + bf_lo(h3.x));
        a1 += (bf_hi(h0.x) + bf_hi(h1.x)) + (bf_hi(h2.x) + bf_hi(h3.x));
        a2 += (bf_lo(h0.y) + bf_lo(h1.y)) + (bf_lo(h2.y) + bf_lo(h3.y));
        a3 += (bf_hi(h0.y) + bf_hi(h1.y)) + (bf_hi(h2.y) + bf_hi(h3.y));
        a4 += (bf_lo(h0.z) + bf_lo(h1.z)) + (bf_lo(h2.z) + bf_lo(h3.z));
        a5 += (bf_hi(h0.z) + bf_hi(h1.z)) + (bf_hi(h2.z) + bf_hi(h3.z));
        a6 += (bf_lo(h0.w) + bf_lo(h1.w)) + (bf_lo(h2.w) + bf_lo(h3.w));
        a7 += (bf_hi(h0.w) + bf_hi(h1.w)) + (bf_hi(h2.w) + bf_hi(h3.w));
    }
    for (; k < end; ++k) {
        int s = csr_src[k];
        uint4 h = H4[(long)s * TPN + lane];
        a0 += bf_lo(h.x); a1 += bf_hi(h.x);
        a2 += bf_lo(h.y); a3 += bf_hi(h.y);
        a4 += bf_lo(h.z); a5 += bf_hi(h.z);
        a6 += bf_lo(h.w); a7 += bf_hi(h.w);
    }

    a0 *= dd; a1 *= dd; a2 *= dd; a3 *= dd;
    a4 *= dd; a5 *= dd; a6 *= dd; a7 *= dd;
    if (BIAS_RELU) {
        const float4 b0 = *(const float4*)&bias[lane * 8];
        const float4 b1 = *(const float4*)&bias[lane * 8 + 4];
        a0 = fmaxf(a0 + b0.x, 0.f); a1 = fmaxf(a1 + b0.y, 0.f);
        a2 = fmaxf(a2 + b0.z, 0.f); a3 = fmaxf(a3 + b0.w, 0.f);
        a4 = fmaxf(a4 + b1.x, 0.f); a5 = fmaxf(a5 + b1.y, 0.f);
        a6 = fmaxf(a6 + b1.z, 0.f); a7 = fmaxf(a7 + b1.w, 0.f);
    }
    float* o = &OUT[(long)node * C + lane * 8];
    *(float4*)(o + 0) = make_float4(a0, a1, a2, a3);
    *(float4*)(o + 4) = make_float4(a4, a5, a6, a7);
}

// ---------------- two-stage per-graph mean pool (batch sorted) ----------------
__global__ __launch_bounds__(256) void k_pool1(const float* __restrict__ H,
                                               const int* __restrict__ batch,
                                               float* __restrict__ partial) {
    const int g = blockIdx.x / PSPLIT;
    const int s = blockIdx.x % PSPLIT;
    int beg, end;
    {
        int lo = 0, hi = NN;
        while (lo < hi) { int mid = (lo + hi) >> 1; if (batch[mid] < g) lo = mid + 1; else hi = mid; }
        beg = lo;
        lo = beg; hi = NN;
        while (lo < hi) { int mid = (lo + hi) >> 1; if (batch[mid] < g + 1) lo = mid + 1; else hi = mid; }
        end = lo;
    }
    const int c4 = threadIdx.x & 15;   // float4 channel group (64 ch = 16 float4)
    const int rg = threadIdx.x >> 4;   // 0..15 node subgroup
    const float4* __restrict__ H4 = (const float4*)H;

    float4 acc = make_float4(0.f, 0.f, 0.f, 0.f);
    for (int n = beg + s * 16 + rg; n < end; n += PSPLIT * 16) {
        float4 h = H4[(long)n * 16 + c4];
        acc.x += h.x; acc.y += h.y; acc.z += h.z; acc.w += h.w;
    }
    __shared__ float4 red[16][17];
    red[rg][c4] = acc;
    __syncthreads();
    if (rg == 0) {
        float4 t = red[0][c4];
#pragma unroll
        for (int i = 1; i < 16; ++i) {
            float4 u = red[i][c4];
            t.x += u.x; t.y += u.y; t.z += u.z; t.w += u.w;
        }
        ((float4*)partial)[(long)blockIdx.x * 16 + c4] = t;
    }
}

__global__ __launch_bounds__(64) void k_pool2(const float* __restrict__ partial,
                                              const int* __restrict__ batch,
                                              const float* __restrict__ b2,
                                              float* __restrict__ out) {
    const int g = blockIdx.x;
    const int ch = threadIdx.x;
    int beg, end;
    {
        int lo = 0, hi = NN;
        while (lo < hi) { int mid = (lo + hi) >> 1; if (batch[mid] < g) lo = mid + 1; else hi = mid; }
        beg = lo;
        lo = beg; hi = NN;
        while (lo < hi) { int mid = (lo + hi) >> 1; if (batch[mid] < g + 1) lo = mid + 1; else hi = mid; }
        end = lo;
    }
    float s = 0.f;
    for (int i = 0; i < PSPLIT; ++i) s += partial[(long)(g * PSPLIT + i) * 64 + ch];
    int cnt = end - beg;
    out[g * 64 + ch] = (cnt > 0) ? (s / (float)cnt + b2[ch]) : 0.f;
}

extern "C" void kernel_launch(void* const* d_in, const int* in_sizes, int n_in,
                              void* d_out, int out_size, void* d_ws, size_t ws_size,
                              hipStream_t stream) {
    const float* x  = (const float*)d_in[0];
    const float* W1 = (const float*)d_in[1];
    const float* b1 = (const float*)d_in[2];
    const float* W2 = (const float*)d_in[3];
    const float* b2 = (const float*)d_in[4];
    const int* ei   = (const int*)d_in[5];
    const int* src  = ei;
    const int* dst  = ei + NE;
    const int* batch = (const int*)d_in[6];
    float* out = (float*)d_out;

    char* p = (char*)d_ws;
    int* deg       = (int*)p;          p += (size_t)NN * 4;
    int* rowptr    = (int*)p;          p += (size_t)(NN + 4) * 4;
    int* cursor    = (int*)p;          p += (size_t)NN * 4;
    int* csr_src   = (int*)p;          p += (size_t)NE * 4;
    int* blockSums = (int*)p;          p += (size_t)64 * 4;
    int* blockOffs = (int*)p;          p += (size_t)64 * 4;
    float* dinv    = (float*)p;        p += (size_t)NN * 4;
    float* partial = (float*)p;        p += (size_t)NG * PSPLIT * 64 * 4;
    ushort_t* Hb   = (ushort_t*)p;     p += (size_t)NN * 128 * 2;   // bf16 GEMM output
    float* bufA    = (float*)p;        p += (size_t)NN * 128 * 4;   // f32 agg output (l2) / pool input
    float* bufB    = (float*)p;        p += (size_t)NN * 128 * 4;   // f32 agg output (l1)

    // ---- CSR build + normalization ----
    k_zero_deg<<<(NN + 255) / 256, 256, 0, stream>>>(deg);
    k_hist<<<(NE + 255) / 256, 256, 0, stream>>>(dst, deg);
    k_scan1<<<SCAN_NB, SCAN_T, 0, stream>>>(deg, blockSums);
    k_scan2<<<1, 64, 0, stream>>>(blockSums, blockOffs);
    k_scan3<<<SCAN_NB, SCAN_T, 0, stream>>>(deg, blockOffs, rowptr, cursor, dinv);
    k_scatter<<<(NE + 255) / 256, 256, 0, stream>>>(src, dst, cursor, csr_src);

    // ---- layer 1: C=128 -> 128 ----
    k_gemm<128, 128, 32><<<(NN + 63) / 64, 256, 0, stream>>>(x, W1, dinv, Hb);   // Hb = bf16((x@W1)*dinv)
    k_agg<128, true><<<(NN + 15) / 16, 256, 0, stream>>>(rowptr, csr_src, dinv, Hb, b1, bufB);

    // ---- layer 2: C=128 -> 64 ----
    k_gemm<128, 64, 64><<<(NN + 63) / 64, 256, 0, stream>>>(bufB, W2, dinv, Hb); // Hb = bf16((h1@W2)*dinv)
    k_agg<64, false><<<(NN + 31) / 32, 256, 0, stream>>>(rowptr, csr_src, dinv, Hb, b2 /*unused*/, bufA);

    // ---- two-stage per-graph mean pool (+b2) ----
    k_pool1<<<NG * PSPLIT, 256, 0, stream>>>(bufA, batch, partial);
    k_pool2<<<NG, 64, 0, stream>>>(partial, batch, b2, out);
}

// Round 9
// 187.728 us; speedup vs baseline: 1.0920x; 1.0920x over previous
//
#include <hip/hip_runtime.h>

#define NN 50000
#define NE 600000
#define NG 64
#define SCAN_T 1024
#define SCAN_NB ((NN + SCAN_T - 1) / SCAN_T)  // 49
#define PSPLIT 16

typedef unsigned int uint_t;
typedef unsigned short ushort_t;

__device__ __forceinline__ ushort_t f2bf(float x) {
    uint_t u = __builtin_bit_cast(uint_t, x);
    u = (u + 0x7FFFu + ((u >> 16) & 1u)) >> 16;  // round-to-nearest-even
    return (ushort_t)u;
}
__device__ __forceinline__ float bf_lo(uint_t p) {
    uint_t v = p << 16; return __builtin_bit_cast(float, v);
}
__device__ __forceinline__ float bf_hi(uint_t p) {
    uint_t v = p & 0xFFFF0000u; return __builtin_bit_cast(float, v);
}

// ---------------- degree histogram (int) ----------------
__global__ void k_zero_deg(int* __restrict__ deg) {
    int i = blockIdx.x * blockDim.x + threadIdx.x;
    if (i < NN) deg[i] = 0;
}

__global__ void k_hist(const int* __restrict__ dst, int* __restrict__ deg) {
    int e = blockIdx.x * blockDim.x + threadIdx.x;
    if (e < NE) atomicAdd(&deg[dst[e]], 1);
}

// ---------------- 3-level parallel exclusive scan ----------------
__global__ __launch_bounds__(SCAN_T) void k_scan1(const int* __restrict__ deg,
                                                  int* __restrict__ blockSums) {
    __shared__ int s[SCAN_T];
    int i = blockIdx.x * SCAN_T + threadIdx.x;
    s[threadIdx.x] = (i < NN) ? deg[i] : 0;
    __syncthreads();
    for (int off = SCAN_T / 2; off > 0; off >>= 1) {
        if (threadIdx.x < off) s[threadIdx.x] += s[threadIdx.x + off];
        __syncthreads();
    }
    if (threadIdx.x == 0) blockSums[blockIdx.x] = s[0];
}

__global__ void k_scan2(const int* __restrict__ blockSums, int* __restrict__ blockOffs) {
    int t = threadIdx.x;  // one wave (64 lanes), SCAN_NB=49 <= 64
    int orig = (t < SCAN_NB) ? blockSums[t] : 0;
    int v = orig;
    for (int off = 1; off < 64; off <<= 1) {
        int u = __shfl_up(v, off);
        if (t >= off) v += u;
    }
    if (t < SCAN_NB) blockOffs[t] = v - orig;  // exclusive
}

__global__ __launch_bounds__(SCAN_T) void k_scan3(const int* __restrict__ deg,
                                                  const int* __restrict__ blockOffs,
                                                  int* __restrict__ rowptr,
                                                  int* __restrict__ cursor,
                                                  float* __restrict__ dinv) {
    __shared__ int s[SCAN_T];
    const int t = threadIdx.x;
    const int i = blockIdx.x * SCAN_T + t;
    const int v = (i < NN) ? deg[i] : 0;
    s[t] = v;
    __syncthreads();
    for (int off = 1; off < SCAN_T; off <<= 1) {
        int u = (t >= off) ? s[t - off] : 0;
        int cur = s[t];
        __syncthreads();
        s[t] = cur + u;
        __syncthreads();
    }
    if (i < NN) {
        int ex = blockOffs[blockIdx.x] + s[t] - v;  // exclusive prefix
        rowptr[i] = ex;
        cursor[i] = ex;
        dinv[i] = rsqrtf((float)(v + 1));
    }
    if (i == 0) rowptr[NN] = NE;  // every edge's dst is in-range
}

// ---------------- scatter edges into CSR buckets ----------------
__global__ void k_scatter(const int* __restrict__ src, const int* __restrict__ dst,
                          int* __restrict__ cursor, int* __restrict__ csr_src) {
    int e = blockIdx.x * blockDim.x + threadIdx.x;
    if (e >= NE) return;
    int d = dst[e];
    int p = atomicAdd(&cursor[d], 1);
    csr_src[p] = src[e];
}

// ---------------- register-blocked GEMM (R7 form), writes pre-scaled bf16 ----------------
// Hb[row] = bf16( (X @ W)[row] * dinv[row] )
template <int CIN, int COUT, int RPT>
__global__ __launch_bounds__(256) void k_gemm(const float* __restrict__ X,
                                              const float* __restrict__ W,
                                              const float* __restrict__ dinv,
                                              ushort_t* __restrict__ Hb) {
    constexpr int TPR = COUT / 4;        // threads across cols
    constexpr int NGRP = 256 / TPR;      // row groups
    constexpr int BM = NGRP * RPT;       // rows per block
    constexpr int LDW = CIN + 4;         // LDS row stride (pad, keeps 16B align)
    constexpr int F4R = CIN / 4;
    __shared__ float xs[BM][LDW];
    const int tid = threadIdx.x;
    const int row0 = blockIdx.x * BM;

    for (int idx = tid; idx < BM * F4R; idx += 256) {
        int r = idx / F4R, c4 = idx % F4R;
        int row = row0 + r;
        float4 v = make_float4(0.f, 0.f, 0.f, 0.f);
        if (row < NN) v = ((const float4*)X)[(long)row * F4R + c4];
        *(float4*)&xs[r][c4 * 4] = v;
    }
    __syncthreads();

    const int g = tid / TPR;             // row group
    const int j = (tid % TPR) * 4;       // col
    const int r0 = g * RPT;

    float4 acc[RPT];
#pragma unroll
    for (int r = 0; r < RPT; ++r) acc[r] = make_float4(0.f, 0.f, 0.f, 0.f);

    for (int k = 0; k < CIN; k += 4) {
        const float4 w0 = *(const float4*)&W[(k + 0) * COUT + j];
        const float4 w1 = *(const float4*)&W[(k + 1) * COUT + j];
        const float4 w2 = *(const float4*)&W[(k + 2) * COUT + j];
        const float4 w3 = *(const float4*)&W[(k + 3) * COUT + j];
#pragma unroll
        for (int r = 0; r < RPT; ++r) {
            const float4 xv = *(const float4*)&xs[r0 + r][k];
            acc[r].x += xv.x * w0.x + xv.y * w1.x + xv.z * w2.x + xv.w * w3.x;
            acc[r].y += xv.x * w0.y + xv.y * w1.y + xv.z * w2.y + xv.w * w3.y;
            acc[r].z += xv.x * w0.z + xv.y * w1.z + xv.z * w2.z + xv.w * w3.z;
            acc[r].w += xv.x * w0.w + xv.y * w1.w + xv.z * w2.w + xv.w * w3.w;
        }
    }

#pragma unroll
    for (int r = 0; r < RPT; ++r) {
        int row = row0 + r0 + r;
        if (row < NN) {
            float sc = dinv[row];
            ushort4 o;
            o.x = f2bf(acc[r].x * sc);
            o.y = f2bf(acc[r].y * sc);
            o.z = f2bf(acc[r].z * sc);
            o.w = f2bf(acc[r].w * sc);
            *(ushort4*)&Hb[(long)row * COUT + j] = o;
        }
    }
}

// ---------------- gather aggregation on pre-scaled bf16 Hb ----------------
// acc = Hb[d] + sum_in Hb[s]  (f32 accumulate), then:
//   EPI==0 (layer1): out_bf16[d] = bf16( relu(dd*acc + bias) * dd )   [next layer operand]
//   EPI==1 (layer2): out_f32[d]  = dd*acc                             [pool input]
template <int C, int EPI>
__global__ __launch_bounds__(256) void k_agg(const int* __restrict__ rowptr,
                                             const int* __restrict__ csr_src,
                                             const float* __restrict__ dinv,
                                             const ushort_t* __restrict__ Hb,
                                             const float* __restrict__ bias,
                                             void* __restrict__ OUT) {
    constexpr int TPN = C / 8;        // threads per node (uint4 = 8 bf16 channels)
    constexpr int NPB = 256 / TPN;    // nodes per block
    const int node = blockIdx.x * NPB + threadIdx.x / TPN;
    if (node >= NN) return;
    const int lane = threadIdx.x % TPN;
    const float dd = dinv[node];
    const uint4* __restrict__ H4 = (const uint4*)Hb;

    float a0, a1, a2, a3, a4, a5, a6, a7;
    {
        uint4 sv = H4[(long)node * TPN + lane];  // self term (pre-scaled)
        a0 = bf_lo(sv.x); a1 = bf_hi(sv.x);
        a2 = bf_lo(sv.y); a3 = bf_hi(sv.y);
        a4 = bf_lo(sv.z); a5 = bf_hi(sv.z);
        a6 = bf_lo(sv.w); a7 = bf_hi(sv.w);
    }

    const int beg = rowptr[node], end = rowptr[node + 1];
    int k = beg;
    const int n4 = beg + ((end - beg) & ~3);
    for (; k < n4; k += 4) {
        int s0 = csr_src[k + 0];
        int s1 = csr_src[k + 1];
        int s2 = csr_src[k + 2];
        int s3 = csr_src[k + 3];
        uint4 h0 = H4[(long)s0 * TPN + lane];
        uint4 h1 = H4[(long)s1 * TPN + lane];
        uint4 h2 = H4[(long)s2 * TPN + lane];
        uint4 h3 = H4[(long)s3 * TPN + lane];
        a0 += (bf_lo(h0.x) + bf_lo(h1.x)) + (bf_lo(h2.x) + bf_lo(h3.x));
        a1 += (bf_hi(h0.x) + bf_hi(h1.x)) + (bf_hi(h2.x) + bf_hi(h3.x));
        a2 += (bf_lo(h0.y) + bf_lo(h1.y)) + (bf_lo(h2.y) + bf_lo(h3.y));
        a3 += (bf_hi(h0.y) + bf_hi(h1.y)) + (bf_hi(h2.y) + bf_hi(h3.y));
        a4 += (bf_lo(h0.z) + bf_lo(h1.z)) + (bf_lo(h2.z) + bf_lo(h3.z));
        a5 += (bf_hi(h0.z) + bf_hi(h1.z)) + (bf_hi(h2.z) + bf_hi(h3.z));
        a6 += (bf_lo(h0.w) + bf_lo(h1.w)) + (bf_lo(h2.w) + bf_lo(h3.w));
        a7 += (bf_hi(h0.w) + bf_hi(h1.w)) + (bf_hi(h2.w) + bf_hi(h3.w));
    }
    for (; k < end; ++k) {
        int s = csr_src[k];
        uint4 h = H4[(long)s * TPN + lane];
        a0 += bf_lo(h.x); a1 += bf_hi(h.x);
        a2 += bf_lo(h.y); a3 += bf_hi(h.y);
        a4 += bf_lo(h.z); a5 += bf_hi(h.z);
        a6 += bf_lo(h.w); a7 += bf_hi(h.w);
    }

    a0 *= dd; a1 *= dd; a2 *= dd; a3 *= dd;
    a4 *= dd; a5 *= dd; a6 *= dd; a7 *= dd;

    if (EPI == 0) {
        const float4 b0 = *(const float4*)&bias[lane * 8];
        const float4 b1 = *(const float4*)&bias[lane * 8 + 4];
        a0 = fmaxf(a0 + b0.x, 0.f) * dd; a1 = fmaxf(a1 + b0.y, 0.f) * dd;
        a2 = fmaxf(a2 + b0.z, 0.f) * dd; a3 = fmaxf(a3 + b0.w, 0.f) * dd;
        a4 = fmaxf(a4 + b1.x, 0.f) * dd; a5 = fmaxf(a5 + b1.y, 0.f) * dd;
        a6 = fmaxf(a6 + b1.z, 0.f) * dd; a7 = fmaxf(a7 + b1.w, 0.f) * dd;
        uint4 o;
        o.x = (uint_t)f2bf(a0) | ((uint_t)f2bf(a1) << 16);
        o.y = (uint_t)f2bf(a2) | ((uint_t)f2bf(a3) << 16);
        o.z = (uint_t)f2bf(a4) | ((uint_t)f2bf(a5) << 16);
        o.w = (uint_t)f2bf(a6) | ((uint_t)f2bf(a7) << 16);
        ((uint4*)OUT)[(long)node * TPN + lane] = o;
    } else {
        float* o = (float*)OUT + (long)node * C + lane * 8;
        *(float4*)(o + 0) = make_float4(a0, a1, a2, a3);
        *(float4*)(o + 4) = make_float4(a4, a5, a6, a7);
    }
}

// ---------------- two-stage per-graph mean pool over C=128, then @W2+b2 ----------------
template <int C>
__global__ __launch_bounds__(256) void k_pool1(const float* __restrict__ H,
                                               const int* __restrict__ batch,
                                               float* __restrict__ partial) {
    constexpr int F4 = C / 4;          // float4 groups per row (32)
    constexpr int SUB = 256 / F4;      // node subgroups (8)
    const int g = blockIdx.x / PSPLIT;
    const int s = blockIdx.x % PSPLIT;
    int beg, end;
    {
        int lo = 0, hi = NN;
        while (lo < hi) { int mid = (lo + hi) >> 1; if (batch[mid] < g) lo = mid + 1; else hi = mid; }
        beg = lo;
        lo = beg; hi = NN;
        while (lo < hi) { int mid = (lo + hi) >> 1; if (batch[mid] < g + 1) lo = mid + 1; else hi = mid; }
        end = lo;
    }
    const int c4 = threadIdx.x % F4;
    const int rg = threadIdx.x / F4;   // 0..SUB-1
    const float4* __restrict__ H4 = (const float4*)H;

    float4 acc = make_float4(0.f, 0.f, 0.f, 0.f);
    for (int n = beg + s * SUB + rg; n < end; n += PSPLIT * SUB) {
        float4 h = H4[(long)n * F4 + c4];
        acc.x += h.x; acc.y += h.y; acc.z += h.z; acc.w += h.w;
    }
    __shared__ float4 red[SUB][F4 + 1];
    red[rg][c4] = acc;
    __syncthreads();
    if (rg == 0) {
        float4 t = red[0][c4];
#pragma unroll
        for (int i = 1; i < SUB; ++i) {
            float4 u = red[i][c4];
            t.x += u.x; t.y += u.y; t.z += u.z; t.w += u.w;
        }
        ((float4*)partial)[(long)blockIdx.x * F4 + c4] = t;
    }
}

// reduce PSPLIT partials -> P_g[128] (mean), then out[g] = P_g @ W2 + b2
__global__ __launch_bounds__(128) void k_pool2gemm(const float* __restrict__ partial,
                                                   const int* __restrict__ batch,
                                                   const float* __restrict__ W2,
                                                   const float* __restrict__ b2,
                                                   float* __restrict__ out) {
    const int g = blockIdx.x;
    const int t = threadIdx.x;  // 0..127
    int beg, end;
    {
        int lo = 0, hi = NN;
        while (lo < hi) { int mid = (lo + hi) >> 1; if (batch[mid] < g) lo = mid + 1; else hi = mid; }
        beg = lo;
        lo = beg; hi = NN;
        while (lo < hi) { int mid = (lo + hi) >> 1; if (batch[mid] < g + 1) lo = mid + 1; else hi = mid; }
        end = lo;
    }
    const int cnt = end - beg;
    __shared__ float P[128];
    float s = 0.f;
    for (int i = 0; i < PSPLIT; ++i) s += partial[(long)(g * PSPLIT + i) * 128 + t];
    P[t] = (cnt > 0) ? s / (float)cnt : 0.f;
    __syncthreads();
    if (t < 64) {
        float acc = 0.f;
        for (int k = 0; k < 128; ++k) acc += P[k] * W2[k * 64 + t];
        out[g * 64 + t] = (cnt > 0) ? acc + b2[t] : 0.f;
    }
}

extern "C" void kernel_launch(void* const* d_in, const int* in_sizes, int n_in,
                              void* d_out, int out_size, void* d_ws, size_t ws_size,
                              hipStream_t stream) {
    const float* x  = (const float*)d_in[0];
    const float* W1 = (const float*)d_in[1];
    const float* b1 = (const float*)d_in[2];
    const float* W2 = (const float*)d_in[3];
    const float* b2 = (const float*)d_in[4];
    const int* ei   = (const int*)d_in[5];
    const int* src  = ei;
    const int* dst  = ei + NE;
    const int* batch = (const int*)d_in[6];
    float* out = (float*)d_out;

    char* p = (char*)d_ws;
    int* deg       = (int*)p;          p += (size_t)NN * 4;
    int* rowptr    = (int*)p;          p += (size_t)(NN + 4) * 4;
    int* cursor    = (int*)p;          p += (size_t)NN * 4;
    int* csr_src   = (int*)p;          p += (size_t)NE * 4;
    int* blockSums = (int*)p;          p += (size_t)64 * 4;
    int* blockOffs = (int*)p;          p += (size_t)64 * 4;
    float* dinv    = (float*)p;        p += (size_t)NN * 4;
    float* partial = (float*)p;        p += (size_t)NG * PSPLIT * 128 * 4;
    ushort_t* Hb   = (ushort_t*)p;     p += (size_t)NN * 128 * 2;   // bf16 gemm1 output (pre-scaled)
    ushort_t* H1b  = (ushort_t*)p;     p += (size_t)NN * 128 * 2;   // bf16 layer1 output (pre-scaled)
    float* bufV    = (float*)p;        p += (size_t)NN * 128 * 4;   // f32 layer2 agg output

    // ---- CSR build + normalization ----
    k_zero_deg<<<(NN + 255) / 256, 256, 0, stream>>>(deg);
    k_hist<<<(NE + 255) / 256, 256, 0, stream>>>(dst, deg);
    k_scan1<<<SCAN_NB, SCAN_T, 0, stream>>>(deg, blockSums);
    k_scan2<<<1, 64, 0, stream>>>(blockSums, blockOffs);
    k_scan3<<<SCAN_NB, SCAN_T, 0, stream>>>(deg, blockOffs, rowptr, cursor, dinv);
    k_scatter<<<(NE + 255) / 256, 256, 0, stream>>>(src, dst, cursor, csr_src);

    // ---- layer 1: gemm + aggregate (+bias,relu), emit bf16 pre-scaled operand ----
    k_gemm<128, 128, 8><<<(NN + 63) / 64, 256, 0, stream>>>(x, W1, dinv, Hb);
    k_agg<128, 0><<<(NN + 15) / 16, 256, 0, stream>>>(rowptr, csr_src, dinv, Hb, b1, H1b);

    // ---- layer 2: aggregate only (W2 commuted past pooling) ----
    k_agg<128, 1><<<(NN + 15) / 16, 256, 0, stream>>>(rowptr, csr_src, dinv, H1b, b1 /*unused*/, bufV);

    // ---- pool (128 ch) then tiny @W2 + b2 ----
    k_pool1<128><<<NG * PSPLIT, 256, 0, stream>>>(bufV, batch, partial);
    k_pool2gemm<<<NG, 128, 0, stream>>>(partial, batch, W2, b2, out);
}

// Round 10
// 167.984 us; speedup vs baseline: 1.2204x; 1.1175x over previous
//
#include <hip/hip_runtime.h>

#define NN 50000
#define NE 600000
#define NG 64
#define SCAN_T 1024
#define SCAN_NB ((NN + SCAN_T - 1) / SCAN_T)  // 49
#define PSPLIT 16

typedef unsigned int uint_t;
typedef unsigned short ushort_t;
typedef __attribute__((ext_vector_type(8))) short bf16x8;
typedef __attribute__((ext_vector_type(4))) float f32x4;

__device__ __forceinline__ ushort_t f2bf(float x) {
    uint_t u = __builtin_bit_cast(uint_t, x);
    u = (u + 0x7FFFu + ((u >> 16) & 1u)) >> 16;  // round-to-nearest-even
    return (ushort_t)u;
}
__device__ __forceinline__ float bf_lo(uint_t p) {
    uint_t v = p << 16; return __builtin_bit_cast(float, v);
}
__device__ __forceinline__ float bf_hi(uint_t p) {
    uint_t v = p & 0xFFFF0000u; return __builtin_bit_cast(float, v);
}

// ---------------- degree histogram (int) ----------------
__global__ void k_zero_deg(int* __restrict__ deg) {
    int i = blockIdx.x * blockDim.x + threadIdx.x;
    if (i < NN) deg[i] = 0;
}

__global__ void k_hist(const int* __restrict__ dst, int* __restrict__ deg) {
    int e = blockIdx.x * blockDim.x + threadIdx.x;
    if (e < NE) atomicAdd(&deg[dst[e]], 1);
}

// ---------------- 3-level parallel exclusive scan ----------------
__global__ __launch_bounds__(SCAN_T) void k_scan1(const int* __restrict__ deg,
                                                  int* __restrict__ blockSums) {
    __shared__ int s[SCAN_T];
    int i = blockIdx.x * SCAN_T + threadIdx.x;
    s[threadIdx.x] = (i < NN) ? deg[i] : 0;
    __syncthreads();
    for (int off = SCAN_T / 2; off > 0; off >>= 1) {
        if (threadIdx.x < off) s[threadIdx.x] += s[threadIdx.x + off];
        __syncthreads();
    }
    if (threadIdx.x == 0) blockSums[blockIdx.x] = s[0];
}

__global__ void k_scan2(const int* __restrict__ blockSums, int* __restrict__ blockOffs) {
    int t = threadIdx.x;  // one wave (64 lanes), SCAN_NB=49 <= 64
    int orig = (t < SCAN_NB) ? blockSums[t] : 0;
    int v = orig;
    for (int off = 1; off < 64; off <<= 1) {
        int u = __shfl_up(v, off);
        if (t >= off) v += u;
    }
    if (t < SCAN_NB) blockOffs[t] = v - orig;  // exclusive
}

__global__ __launch_bounds__(SCAN_T) void k_scan3(const int* __restrict__ deg,
                                                  const int* __restrict__ blockOffs,
                                                  int* __restrict__ rowptr,
                                                  int* __restrict__ cursor,
                                                  float* __restrict__ dinv) {
    __shared__ int s[SCAN_T];
    const int t = threadIdx.x;
    const int i = blockIdx.x * SCAN_T + t;
    const int v = (i < NN) ? deg[i] : 0;
    s[t] = v;
    __syncthreads();
    for (int off = 1; off < SCAN_T; off <<= 1) {
        int u = (t >= off) ? s[t - off] : 0;
        int cur = s[t];
        __syncthreads();
        s[t] = cur + u;
        __syncthreads();
    }
    if (i < NN) {
        int ex = blockOffs[blockIdx.x] + s[t] - v;  // exclusive prefix
        rowptr[i] = ex;
        cursor[i] = ex;
        dinv[i] = rsqrtf((float)(v + 1));
    }
    if (i == 0) rowptr[NN] = NE;  // every edge's dst is in-range
}

// ---------------- scatter edges into CSR buckets ----------------
__global__ void k_scatter(const int* __restrict__ src, const int* __restrict__ dst,
                          int* __restrict__ cursor, int* __restrict__ csr_src) {
    int e = blockIdx.x * blockDim.x + threadIdx.x;
    if (e >= NE) return;
    int d = dst[e];
    int p = atomicAdd(&cursor[d], 1);
    csr_src[p] = src[e];
}

// ---------------- W1 prep: Wt[n][k] = bf16(W1[k][n]) ----------------
__global__ void k_wprep(const float* __restrict__ W, ushort_t* __restrict__ Wt) {
    int idx = blockIdx.x * 256 + threadIdx.x;  // 16384 = 128*128
    if (idx >= 128 * 128) return;
    int k = idx >> 7, n = idx & 127;
    Wt[n * 128 + k] = f2bf(W[idx]);            // coalesced read W[k][n]
}

// ---------------- bf16 MFMA GEMM: Hb = bf16((X @ W1) * dinv) ----------------
// Block: 256 thr (4 waves), 128 rows x 128 cols, K=128.
// xs/ws: row-major bf16 [128][128] with XOR swizzle byte^=((r&7)<<4).
// Wave w: mtiles (w>>1)*4+{0..3}, ntiles (w&1)*4+{0..3}; 16x16x32 MFMA.
__global__ __launch_bounds__(256) void k_gemm_mfma(const float* __restrict__ X,
                                                   const ushort_t* __restrict__ Wt,
                                                   const float* __restrict__ dinv,
                                                   ushort_t* __restrict__ Hb) {
    __shared__ ushort_t xs[128 * 128];   // 32 KB
    __shared__ ushort_t ws[128 * 128];   // 32 KB
    const int tid = threadIdx.x;
    const int row0 = blockIdx.x * 128;

    // stage X tile: f32 -> bf16, swizzled
    for (int idx = tid; idx < 128 * 32; idx += 256) {   // 32 float4-groups per row
        int r = idx >> 5, c4 = idx & 31;
        int row = row0 + r;
        float4 v = make_float4(0.f, 0.f, 0.f, 0.f);
        if (row < NN) v = ((const float4*)X)[(long)row * 32 + c4];
        ushort4 o;
        o.x = f2bf(v.x); o.y = f2bf(v.y); o.z = f2bf(v.z); o.w = f2bf(v.w);
        uint_t byte = (uint_t)(r * 256 + c4 * 8) ^ (uint_t)((r & 7) << 4);
        *(ushort4*)((char*)xs + byte) = o;
    }
    // stage Wt (already bf16), swizzled
    for (int idx = tid; idx < 128 * 16; idx += 256) {   // 16 x 16B units per row
        int n = idx >> 4, c16 = idx & 15;
        uint4 v = ((const uint4*)Wt)[idx];
        uint_t byte = (uint_t)(n * 256 + c16 * 16) ^ (uint_t)((n & 7) << 4);
        *(uint4*)((char*)ws + byte) = v;
    }
    __syncthreads();

    const int w = tid >> 6;
    const int l = tid & 63;
    const int m0 = (w >> 1) * 4;   // mtile base
    const int n0 = (w & 1) * 4;    // ntile base
    const int lr = l & 15;
    const int kg = l >> 4;

    f32x4 acc[4][4] = {};
    for (int kk = 0; kk < 4; ++kk) {
        const int kb = kk * 64 + kg * 16;  // byte offset of this lane's 8 bf16 k-elems
        bf16x8 a[4], b[4];
#pragma unroll
        for (int m = 0; m < 4; ++m) {
            int r = (m0 + m) * 16 + lr;
            uint_t byte = (uint_t)(r * 256 + kb) ^ (uint_t)((r & 7) << 4);
            a[m] = *(const bf16x8*)((const char*)xs + byte);
        }
#pragma unroll
        for (int n = 0; n < 4; ++n) {
            int r = (n0 + n) * 16 + lr;
            uint_t byte = (uint_t)(r * 256 + kb) ^ (uint_t)((r & 7) << 4);
            b[n] = *(const bf16x8*)((const char*)ws + byte);
        }
#pragma unroll
        for (int m = 0; m < 4; ++m)
#pragma unroll
            for (int n = 0; n < 4; ++n)
                acc[m][n] = __builtin_amdgcn_mfma_f32_16x16x32_bf16(a[m], b[n], acc[m][n], 0, 0, 0);
    }

    // epilogue: C/D layout col=lane&15, row=(lane>>4)*4+reg
#pragma unroll
    for (int m = 0; m < 4; ++m) {
#pragma unroll
        for (int r = 0; r < 4; ++r) {
            int row = row0 + (m0 + m) * 16 + kg * 4 + r;
            if (row < NN) {
                float sc = dinv[row];
#pragma unroll
                for (int n = 0; n < 4; ++n) {
                    int col = (n0 + n) * 16 + lr;
                    Hb[(long)row * 128 + col] = f2bf(acc[m][n][r] * sc);
                }
            }
        }
    }
}

// ---------------- gather aggregation on pre-scaled bf16 Hb ----------------
// acc = Hb[d] + sum_in Hb[s]  (f32 accumulate), then:
//   EPI==0 (layer1): out_bf16[d] = bf16( relu(dd*acc + bias) * dd )   [next layer operand]
//   EPI==1 (layer2): out_bf16[d] = bf16( dd*acc )                     [pool input]
template <int C, int EPI>
__global__ __launch_bounds__(256) void k_agg(const int* __restrict__ rowptr,
                                             const int* __restrict__ csr_src,
                                             const float* __restrict__ dinv,
                                             const ushort_t* __restrict__ Hb,
                                             const float* __restrict__ bias,
                                             void* __restrict__ OUT) {
    constexpr int TPN = C / 8;        // threads per node (uint4 = 8 bf16 channels)
    constexpr int NPB = 256 / TPN;    // nodes per block
    const int node = blockIdx.x * NPB + threadIdx.x / TPN;
    if (node >= NN) return;
    const int lane = threadIdx.x % TPN;
    const float dd = dinv[node];
    const uint4* __restrict__ H4 = (const uint4*)Hb;

    float a0, a1, a2, a3, a4, a5, a6, a7;
    {
        uint4 sv = H4[(long)node * TPN + lane];  // self term (pre-scaled)
        a0 = bf_lo(sv.x); a1 = bf_hi(sv.x);
        a2 = bf_lo(sv.y); a3 = bf_hi(sv.y);
        a4 = bf_lo(sv.z); a5 = bf_hi(sv.z);
        a6 = bf_lo(sv.w); a7 = bf_hi(sv.w);
    }

    const int beg = rowptr[node], end = rowptr[node + 1];
    int k = beg;
    const int n4 = beg + ((end - beg) & ~3);
    for (; k < n4; k += 4) {
        int s0 = csr_src[k + 0];
        int s1 = csr_src[k + 1];
        int s2 = csr_src[k + 2];
        int s3 = csr_src[k + 3];
        uint4 h0 = H4[(long)s0 * TPN + lane];
        uint4 h1 = H4[(long)s1 * TPN + lane];
        uint4 h2 = H4[(long)s2 * TPN + lane];
        uint4 h3 = H4[(long)s3 * TPN + lane];
        a0 += (bf_lo(h0.x) + bf_lo(h1.x)) + (bf_lo(h2.x) + bf_lo(h3.x));
        a1 += (bf_hi(h0.x) + bf_hi(h1.x)) + (bf_hi(h2.x) + bf_hi(h3.x));
        a2 += (bf_lo(h0.y) + bf_lo(h1.y)) + (bf_lo(h2.y) + bf_lo(h3.y));
        a3 += (bf_hi(h0.y) + bf_hi(h1.y)) + (bf_hi(h2.y) + bf_hi(h3.y));
        a4 += (bf_lo(h0.z) + bf_lo(h1.z)) + (bf_lo(h2.z) + bf_lo(h3.z));
        a5 += (bf_hi(h0.z) + bf_hi(h1.z)) + (bf_hi(h2.z) + bf_hi(h3.z));
        a6 += (bf_lo(h0.w) + bf_lo(h1.w)) + (bf_lo(h2.w) + bf_lo(h3.w));
        a7 += (bf_hi(h0.w) + bf_hi(h1.w)) + (bf_hi(h2.w) + bf_hi(h3.w));
    }
    for (; k < end; ++k) {
        int s = csr_src[k];
        uint4 h = H4[(long)s * TPN + lane];
        a0 += bf_lo(h.x); a1 += bf_hi(h.x);
        a2 += bf_lo(h.y); a3 += bf_hi(h.y);
        a4 += bf_lo(h.z); a5 += bf_hi(h.z);
        a6 += bf_lo(h.w); a7 += bf_hi(h.w);
    }

    a0 *= dd; a1 *= dd; a2 *= dd; a3 *= dd;
    a4 *= dd; a5 *= dd; a6 *= dd; a7 *= dd;

    if (EPI == 0) {
        const float4 b0 = *(const float4*)&bias[lane * 8];
        const float4 b1 = *(const float4*)&bias[lane * 8 + 4];
        a0 = fmaxf(a0 + b0.x, 0.f) * dd; a1 = fmaxf(a1 + b0.y, 0.f) * dd;
        a2 = fmaxf(a2 + b0.z, 0.f) * dd; a3 = fmaxf(a3 + b0.w, 0.f) * dd;
        a4 = fmaxf(a4 + b1.x, 0.f) * dd; a5 = fmaxf(a5 + b1.y, 0.f) * dd;
        a6 = fmaxf(a6 + b1.z, 0.f) * dd; a7 = fmaxf(a7 + b1.w, 0.f) * dd;
    }
    uint4 o;
    o.x = (uint_t)f2bf(a0) | ((uint_t)f2bf(a1) << 16);
    o.y = (uint_t)f2bf(a2) | ((uint_t)f2bf(a3) << 16);
    o.z = (uint_t)f2bf(a4) | ((uint_t)f2bf(a5) << 16);
    o.w = (uint_t)f2bf(a6) | ((uint_t)f2bf(a7) << 16);
    ((uint4*)OUT)[(long)node * TPN + lane] = o;
}

// ---------------- two-stage per-graph mean pool over C=128 bf16, then @W2+b2 ----------------
__global__ __launch_bounds__(256) void k_pool1(const ushort_t* __restrict__ V,
                                               const int* __restrict__ batch,
                                               float* __restrict__ partial) {
    const int g = blockIdx.x / PSPLIT;
    const int s = blockIdx.x % PSPLIT;
    int beg, end;
    {
        int lo = 0, hi = NN;
        while (lo < hi) { int mid = (lo + hi) >> 1; if (batch[mid] < g) lo = mid + 1; else hi = mid; }
        beg = lo;
        lo = beg; hi = NN;
        while (lo < hi) { int mid = (lo + hi) >> 1; if (batch[mid] < g + 1) lo = mid + 1; else hi = mid; }
        end = lo;
    }
    const int c = threadIdx.x & 31;    // uint2 group = 4 channels
    const int rg = threadIdx.x >> 5;   // 0..7 node subgroup
    const uint2* __restrict__ V2 = (const uint2*)V;

    float4 acc = make_float4(0.f, 0.f, 0.f, 0.f);
    for (int n = beg + s * 8 + rg; n < end; n += PSPLIT * 8) {
        uint2 h = V2[(long)n * 32 + c];
        acc.x += bf_lo(h.x); acc.y += bf_hi(h.x);
        acc.z += bf_lo(h.y); acc.w += bf_hi(h.y);
    }
    __shared__ float4 red[8][33];
    red[rg][c] = acc;
    __syncthreads();
    if (rg == 0) {
        float4 t = red[0][c];
#pragma unroll
        for (int i = 1; i < 8; ++i) {
            float4 u = red[i][c];
            t.x += u.x; t.y += u.y; t.z += u.z; t.w += u.w;
        }
        ((float4*)partial)[(long)blockIdx.x * 32 + c] = t;
    }
}

// reduce PSPLIT partials -> P_g[128] (mean), then out[g] = P_g @ W2 + b2
__global__ __launch_bounds__(128) void k_pool2gemm(const float* __restrict__ partial,
                                                   const int* __restrict__ batch,
                                                   const float* __restrict__ W2,
                                                   const float* __restrict__ b2,
                                                   float* __restrict__ out) {
    const int g = blockIdx.x;
    const int t = threadIdx.x;  // 0..127
    int beg, end;
    {
        int lo = 0, hi = NN;
        while (lo < hi) { int mid = (lo + hi) >> 1; if (batch[mid] < g) lo = mid + 1; else hi = mid; }
        beg = lo;
        lo = beg; hi = NN;
        while (lo < hi) { int mid = (lo + hi) >> 1; if (batch[mid] < g + 1) lo = mid + 1; else hi = mid; }
        end = lo;
    }
    const int cnt = end - beg;
    __shared__ float P[128];
    float s = 0.f;
    for (int i = 0; i < PSPLIT; ++i) s += partial[(long)(g * PSPLIT + i) * 128 + t];
    P[t] = (cnt > 0) ? s / (float)cnt : 0.f;
    __syncthreads();
    if (t < 64) {
        float acc = 0.f;
        for (int k = 0; k < 128; ++k) acc += P[k] * W2[k * 64 + t];
        out[g * 64 + t] = (cnt > 0) ? acc + b2[t] : 0.f;
    }
}

extern "C" void kernel_launch(void* const* d_in, const int* in_sizes, int n_in,
                              void* d_out, int out_size, void* d_ws, size_t ws_size,
                              hipStream_t stream) {
    const float* x  = (const float*)d_in[0];
    const float* W1 = (const float*)d_in[1];
    const float* b1 = (const float*)d_in[2];
    const float* W2 = (const float*)d_in[3];
    const float* b2 = (const float*)d_in[4];
    const int* ei   = (const int*)d_in[5];
    const int* src  = ei;
    const int* dst  = ei + NE;
    const int* batch = (const int*)d_in[6];
    float* out = (float*)d_out;

    char* p = (char*)d_ws;
    int* deg       = (int*)p;          p += (size_t)NN * 4;
    int* rowptr    = (int*)p;          p += (size_t)(NN + 4) * 4;
    int* cursor    = (int*)p;          p += (size_t)NN * 4;
    int* csr_src   = (int*)p;          p += (size_t)NE * 4;
    int* blockSums = (int*)p;          p += (size_t)64 * 4;
    int* blockOffs = (int*)p;          p += (size_t)64 * 4;
    float* dinv    = (float*)p;        p += (size_t)NN * 4;
    float* partial = (float*)p;        p += (size_t)NG * PSPLIT * 128 * 4;
    ushort_t* Wt   = (ushort_t*)p;     p += (size_t)128 * 128 * 2;  // bf16 W1^T
    ushort_t* Hb   = (ushort_t*)p;     p += (size_t)NN * 128 * 2;   // bf16 gemm1 output (pre-scaled)
    ushort_t* H1b  = (ushort_t*)p;     p += (size_t)NN * 128 * 2;   // bf16 layer1 output (pre-scaled)
    ushort_t* Vb   = (ushort_t*)p;     p += (size_t)NN * 128 * 2;   // bf16 layer2 agg output

    // ---- CSR build + normalization + W prep ----
    k_wprep<<<64, 256, 0, stream>>>(W1, Wt);
    k_zero_deg<<<(NN + 255) / 256, 256, 0, stream>>>(deg);
    k_hist<<<(NE + 255) / 256, 256, 0, stream>>>(dst, deg);
    k_scan1<<<SCAN_NB, SCAN_T, 0, stream>>>(deg, blockSums);
    k_scan2<<<1, 64, 0, stream>>>(blockSums, blockOffs);
    k_scan3<<<SCAN_NB, SCAN_T, 0, stream>>>(deg, blockOffs, rowptr, cursor, dinv);
    k_scatter<<<(NE + 255) / 256, 256, 0, stream>>>(src, dst, cursor, csr_src);

    // ---- layer 1: MFMA gemm + aggregate (+bias,relu), emit bf16 pre-scaled operand ----
    k_gemm_mfma<<<(NN + 127) / 128, 256, 0, stream>>>(x, Wt, dinv, Hb);
    k_agg<128, 0><<<(NN + 15) / 16, 256, 0, stream>>>(rowptr, csr_src, dinv, Hb, b1, H1b);

    // ---- layer 2: aggregate only (W2 commuted past pooling), bf16 out ----
    k_agg<128, 1><<<(NN + 15) / 16, 256, 0, stream>>>(rowptr, csr_src, dinv, H1b, b1 /*unused*/, Vb);

    // ---- pool (128 ch bf16) then tiny @W2 + b2 ----
    k_pool1<<<NG * PSPLIT, 256, 0, stream>>>(Vb, batch, partial);
    k_pool2gemm<<<NG, 128, 0, stream>>>(partial, batch, W2, b2, out);
}

// Round 11
// 159.120 us; speedup vs baseline: 1.2884x; 1.0557x over previous
//
#include <hip/hip_runtime.h>

#define NN 50000
#define NE 600000
#define NG 64
#define SCAN_T 1024
#define SCAN_NB ((NN + SCAN_T - 1) / SCAN_T)  // 49
#define PSPLIT 16

typedef unsigned int uint_t;
typedef unsigned short ushort_t;
typedef __attribute__((ext_vector_type(8))) short bf16x8;
typedef __attribute__((ext_vector_type(4))) float f32x4;

__device__ __forceinline__ ushort_t f2bf(float x) {
    uint_t u = __builtin_bit_cast(uint_t, x);
    u = (u + 0x7FFFu + ((u >> 16) & 1u)) >> 16;  // round-to-nearest-even
    return (ushort_t)u;
}
__device__ __forceinline__ float bf_lo(uint_t p) {
    uint_t v = p << 16; return __builtin_bit_cast(float, v);
}
__device__ __forceinline__ float bf_hi(uint_t p) {
    uint_t v = p & 0xFFFF0000u; return __builtin_bit_cast(float, v);
}

// ---------------- degree histogram (int) ----------------
__global__ void k_zero_deg(int* __restrict__ deg) {
    int i = blockIdx.x * blockDim.x + threadIdx.x;
    if (i < NN) deg[i] = 0;
}

__global__ void k_hist(const int* __restrict__ dst, int* __restrict__ deg) {
    int e = blockIdx.x * blockDim.x + threadIdx.x;
    if (e < NE) atomicAdd(&deg[dst[e]], 1);
}

// ---------------- W prep: W1t[n][k]=bf16(W1[k][n]), W2t[n][k]=bf16(W2[k][n]) ----------------
__global__ void k_wprep(const float* __restrict__ W1, const float* __restrict__ W2,
                        ushort_t* __restrict__ W1t, ushort_t* __restrict__ W2t) {
    int idx = blockIdx.x * 256 + threadIdx.x;
    if (idx < 128 * 128) {
        int k = idx >> 7, n = idx & 127;
        W1t[n * 128 + k] = f2bf(W1[idx]);
    } else if (idx < 128 * 128 + 128 * 64) {
        int j = idx - 128 * 128;
        int k = j >> 6, n = j & 63;
        W2t[n * 128 + k] = f2bf(W2[j]);
    }
}

// ---------------- scan stage 1: per-block sums ----------------
__global__ __launch_bounds__(SCAN_T) void k_scan1(const int* __restrict__ deg,
                                                  int* __restrict__ blockSums) {
    __shared__ int s[SCAN_T];
    int i = blockIdx.x * SCAN_T + threadIdx.x;
    s[threadIdx.x] = (i < NN) ? deg[i] : 0;
    __syncthreads();
    for (int off = SCAN_T / 2; off > 0; off >>= 1) {
        if (threadIdx.x < off) s[threadIdx.x] += s[threadIdx.x + off];
        __syncthreads();
    }
    if (threadIdx.x == 0) blockSums[blockIdx.x] = s[0];
}

// ---------------- scan stage 2+3 fused: block offsets (wave 0, redundant) + intra-block scan ----------------
__global__ __launch_bounds__(SCAN_T) void k_scan3(const int* __restrict__ deg,
                                                  const int* __restrict__ blockSums,
                                                  int* __restrict__ rowptr,
                                                  int* __restrict__ cursor,
                                                  float* __restrict__ dinv) {
    __shared__ int offs[64];
    __shared__ int s[SCAN_T];
    const int t = threadIdx.x;
    if (t < 64) {  // wave 0: exclusive scan of the 49 block sums
        int orig = (t < SCAN_NB) ? blockSums[t] : 0;
        int v = orig;
        for (int off = 1; off < 64; off <<= 1) {
            int u = __shfl_up(v, off);
            if (t >= off) v += u;
        }
        offs[t] = v - orig;
    }
    const int i = blockIdx.x * SCAN_T + t;
    const int v = (i < NN) ? deg[i] : 0;
    s[t] = v;
    __syncthreads();
    for (int off = 1; off < SCAN_T; off <<= 1) {
        int u = (t >= off) ? s[t - off] : 0;
        int cur = s[t];
        __syncthreads();
        s[t] = cur + u;
        __syncthreads();
    }
    if (i < NN) {
        int ex = offs[blockIdx.x] + s[t] - v;  // exclusive prefix
        rowptr[i] = ex;
        cursor[i] = ex;
        dinv[i] = rsqrtf((float)(v + 1));
    }
    if (i == 0) rowptr[NN] = NE;  // every edge's dst is in-range
}

// ---------------- scatter edges into CSR buckets ----------------
__global__ void k_scatter(const int* __restrict__ src, const int* __restrict__ dst,
                          int* __restrict__ cursor, int* __restrict__ csr_src) {
    int e = blockIdx.x * blockDim.x + threadIdx.x;
    if (e >= NE) return;
    int d = dst[e];
    int p = atomicAdd(&cursor[d], 1);
    csr_src[p] = src[e];
}

// ---------------- bf16 MFMA GEMM 1: Hb = bf16((X @ W1) * dinv) ----------------
// Block: 256 thr (4 waves), 128 rows x 128 cols, K=128.
// xs/ws: row-major bf16 [128][128] with XOR swizzle byte^=((r&7)<<4).
__global__ __launch_bounds__(256) void k_gemm_mfma(const float* __restrict__ X,
                                                   const ushort_t* __restrict__ Wt,
                                                   const float* __restrict__ dinv,
                                                   ushort_t* __restrict__ Hb) {
    __shared__ ushort_t xs[128 * 128];   // 32 KB
    __shared__ ushort_t ws[128 * 128];   // 32 KB
    const int tid = threadIdx.x;
    const int row0 = blockIdx.x * 128;

    for (int idx = tid; idx < 128 * 32; idx += 256) {   // X: f32 -> bf16
        int r = idx >> 5, c4 = idx & 31;
        int row = row0 + r;
        float4 v = make_float4(0.f, 0.f, 0.f, 0.f);
        if (row < NN) v = ((const float4*)X)[(long)row * 32 + c4];
        ushort4 o;
        o.x = f2bf(v.x); o.y = f2bf(v.y); o.z = f2bf(v.z); o.w = f2bf(v.w);
        uint_t byte = (uint_t)(r * 256 + c4 * 8) ^ (uint_t)((r & 7) << 4);
        *(ushort4*)((char*)xs + byte) = o;
    }
    for (int idx = tid; idx < 128 * 16; idx += 256) {   // Wt (bf16)
        int n = idx >> 4, c16 = idx & 15;
        uint4 v = ((const uint4*)Wt)[idx];
        uint_t byte = (uint_t)(n * 256 + c16 * 16) ^ (uint_t)((n & 7) << 4);
        *(uint4*)((char*)ws + byte) = v;
    }
    __syncthreads();

    const int w = tid >> 6;
    const int l = tid & 63;
    const int m0 = (w >> 1) * 4;
    const int n0 = (w & 1) * 4;
    const int lr = l & 15;
    const int kg = l >> 4;

    f32x4 acc[4][4] = {};
    for (int kk = 0; kk < 4; ++kk) {
        const int kb = kk * 64 + kg * 16;
        bf16x8 a[4], b[4];
#pragma unroll
        for (int m = 0; m < 4; ++m) {
            int r = (m0 + m) * 16 + lr;
            uint_t byte = (uint_t)(r * 256 + kb) ^ (uint_t)((r & 7) << 4);
            a[m] = *(const bf16x8*)((const char*)xs + byte);
        }
#pragma unroll
        for (int n = 0; n < 4; ++n) {
            int r = (n0 + n) * 16 + lr;
            uint_t byte = (uint_t)(r * 256 + kb) ^ (uint_t)((r & 7) << 4);
            b[n] = *(const bf16x8*)((const char*)ws + byte);
        }
#pragma unroll
        for (int m = 0; m < 4; ++m)
#pragma unroll
            for (int n = 0; n < 4; ++n)
                acc[m][n] = __builtin_amdgcn_mfma_f32_16x16x32_bf16(a[m], b[n], acc[m][n], 0, 0, 0);
    }

#pragma unroll
    for (int m = 0; m < 4; ++m) {
#pragma unroll
        for (int r = 0; r < 4; ++r) {
            int row = row0 + (m0 + m) * 16 + kg * 4 + r;
            if (row < NN) {
                float sc = dinv[row];
#pragma unroll
                for (int n = 0; n < 4; ++n) {
                    int col = (n0 + n) * 16 + lr;
                    Hb[(long)row * 128 + col] = f2bf(acc[m][n][r] * sc);
                }
            }
        }
    }
}

// ---------------- bf16 MFMA GEMM 2: G = bf16((H1 @ W2) * dinv), 128 -> 64 ----------------
// Block: 256 thr (4 waves), 128 rows x 64 cols, K=128. Wave w: mtiles w*2+{0,1}, all 4 ntiles.
__global__ __launch_bounds__(256) void k_gemm_mfma2(const ushort_t* __restrict__ H1,
                                                    const ushort_t* __restrict__ W2t,
                                                    const float* __restrict__ dinv,
                                                    ushort_t* __restrict__ G) {
    __shared__ ushort_t xs[128 * 128];   // 32 KB
    __shared__ ushort_t ws2[64 * 128];   // 16 KB
    const int tid = threadIdx.x;
    const int row0 = blockIdx.x * 128;

    for (int idx = tid; idx < 128 * 16; idx += 256) {   // H1 tile (bf16)
        int r = idx >> 4, c16 = idx & 15;
        int row = row0 + r;
        uint4 v = make_uint4(0u, 0u, 0u, 0u);
        if (row < NN) v = ((const uint4*)H1)[(long)row * 16 + c16];
        uint_t byte = (uint_t)(r * 256 + c16 * 16) ^ (uint_t)((r & 7) << 4);
        *(uint4*)((char*)xs + byte) = v;
    }
    for (int idx = tid; idx < 64 * 16; idx += 256) {    // W2t (bf16)
        int n = idx >> 4, c16 = idx & 15;
        uint4 v = ((const uint4*)W2t)[idx];
        uint_t byte = (uint_t)(n * 256 + c16 * 16) ^ (uint_t)((n & 7) << 4);
        *(uint4*)((char*)ws2 + byte) = v;
    }
    __syncthreads();

    const int w = tid >> 6;
    const int l = tid & 63;
    const int lr = l & 15;
    const int kg = l >> 4;
    const int m0 = w * 2;

    f32x4 acc[2][4] = {};
    for (int kk = 0; kk < 4; ++kk) {
        const int kb = kk * 64 + kg * 16;
        bf16x8 a[2], b[4];
#pragma unroll
        for (int m = 0; m < 2; ++m) {
            int r = (m0 + m) * 16 + lr;
            uint_t byte = (uint_t)(r * 256 + kb) ^ (uint_t)((r & 7) << 4);
            a[m] = *(const bf16x8*)((const char*)xs + byte);
        }
#pragma unroll
        for (int n = 0; n < 4; ++n) {
            int r = n * 16 + lr;
            uint_t byte = (uint_t)(r * 256 + kb) ^ (uint_t)((r & 7) << 4);
            b[n] = *(const bf16x8*)((const char*)ws2 + byte);
        }
#pragma unroll
        for (int m = 0; m < 2; ++m)
#pragma unroll
            for (int n = 0; n < 4; ++n)
                acc[m][n] = __builtin_amdgcn_mfma_f32_16x16x32_bf16(a[m], b[n], acc[m][n], 0, 0, 0);
    }

#pragma unroll
    for (int m = 0; m < 2; ++m) {
#pragma unroll
        for (int r = 0; r < 4; ++r) {
            int row = row0 + (m0 + m) * 16 + kg * 4 + r;
            if (row < NN) {
                float sc = dinv[row];
#pragma unroll
                for (int n = 0; n < 4; ++n) {
                    int col = n * 16 + lr;
                    G[(long)row * 64 + col] = f2bf(acc[m][n][r] * sc);
                }
            }
        }
    }
}

// ---------------- gather aggregation on pre-scaled bf16 ----------------
// acc = Hb[d] + sum_in Hb[s]  (f32 accumulate), then:
//   EPI==0 (layer1, C=128): out_bf16[d] = bf16( relu(dd*acc + bias) )  [gemm2 operand]
//   EPI==1 (layer2, C=64):  out_bf16[d] = bf16( dd*acc )               [pool input]
template <int C, int EPI>
__global__ __launch_bounds__(256) void k_agg(const int* __restrict__ rowptr,
                                             const int* __restrict__ csr_src,
                                             const float* __restrict__ dinv,
                                             const ushort_t* __restrict__ Hb,
                                             const float* __restrict__ bias,
                                             ushort_t* __restrict__ OUT) {
    constexpr int TPN = C / 8;        // threads per node (uint4 = 8 bf16 channels)
    constexpr int NPB = 256 / TPN;    // nodes per block
    const int node = blockIdx.x * NPB + threadIdx.x / TPN;
    if (node >= NN) return;
    const int lane = threadIdx.x % TPN;
    const float dd = dinv[node];
    const uint4* __restrict__ H4 = (const uint4*)Hb;

    float a0, a1, a2, a3, a4, a5, a6, a7;
    {
        uint4 sv = H4[(long)node * TPN + lane];  // self term (pre-scaled)
        a0 = bf_lo(sv.x); a1 = bf_hi(sv.x);
        a2 = bf_lo(sv.y); a3 = bf_hi(sv.y);
        a4 = bf_lo(sv.z); a5 = bf_hi(sv.z);
        a6 = bf_lo(sv.w); a7 = bf_hi(sv.w);
    }

    const int beg = rowptr[node], end = rowptr[node + 1];
    int k = beg;
    const int n4 = beg + ((end - beg) & ~3);
    for (; k < n4; k += 4) {
        int s0 = csr_src[k + 0];
        int s1 = csr_src[k + 1];
        int s2 = csr_src[k + 2];
        int s3 = csr_src[k + 3];
        uint4 h0 = H4[(long)s0 * TPN + lane];
        uint4 h1 = H4[(long)s1 * TPN + lane];
        uint4 h2 = H4[(long)s2 * TPN + lane];
        uint4 h3 = H4[(long)s3 * TPN + lane];
        a0 += (bf_lo(h0.x) + bf_lo(h1.x)) + (bf_lo(h2.x) + bf_lo(h3.x));
        a1 += (bf_hi(h0.x) + bf_hi(h1.x)) + (bf_hi(h2.x) + bf_hi(h3.x));
        a2 += (bf_lo(h0.y) + bf_lo(h1.y)) + (bf_lo(h2.y) + bf_lo(h3.y));
        a3 += (bf_hi(h0.y) + bf_hi(h1.y)) + (bf_hi(h2.y) + bf_hi(h3.y));
        a4 += (bf_lo(h0.z) + bf_lo(h1.z)) + (bf_lo(h2.z) + bf_lo(h3.z));
        a5 += (bf_hi(h0.z) + bf_hi(h1.z)) + (bf_hi(h2.z) + bf_hi(h3.z));
        a6 += (bf_lo(h0.w) + bf_lo(h1.w)) + (bf_lo(h2.w) + bf_lo(h3.w));
        a7 += (bf_hi(h0.w) + bf_hi(h1.w)) + (bf_hi(h2.w) + bf_hi(h3.w));
    }
    for (; k < end; ++k) {
        int s = csr_src[k];
        uint4 h = H4[(long)s * TPN + lane];
        a0 += bf_lo(h.x); a1 += bf_hi(h.x);
        a2 += bf_lo(h.y); a3 += bf_hi(h.y);
        a4 += bf_lo(h.z); a5 += bf_hi(h.z);
        a6 += bf_lo(h.w); a7 += bf_hi(h.w);
    }

    a0 *= dd; a1 *= dd; a2 *= dd; a3 *= dd;
    a4 *= dd; a5 *= dd; a6 *= dd; a7 *= dd;

    if (EPI == 0) {
        const float4 b0 = *(const float4*)&bias[lane * 8];
        const float4 b1 = *(const float4*)&bias[lane * 8 + 4];
        a0 = fmaxf(a0 + b0.x, 0.f); a1 = fmaxf(a1 + b0.y, 0.f);
        a2 = fmaxf(a2 + b0.z, 0.f); a3 = fmaxf(a3 + b0.w, 0.f);
        a4 = fmaxf(a4 + b1.x, 0.f); a5 = fmaxf(a5 + b1.y, 0.f);
        a6 = fmaxf(a6 + b1.z, 0.f); a7 = fmaxf(a7 + b1.w, 0.f);
    }
    uint4 o;
    o.x = (uint_t)f2bf(a0) | ((uint_t)f2bf(a1) << 16);
    o.y = (uint_t)f2bf(a2) | ((uint_t)f2bf(a3) << 16);
    o.z = (uint_t)f2bf(a4) | ((uint_t)f2bf(a5) << 16);
    o.w = (uint_t)f2bf(a6) | ((uint_t)f2bf(a7) << 16);
    ((uint4*)OUT)[(long)node * TPN + lane] = o;
}

// ---------------- two-stage per-graph mean pool over C=64 bf16 ----------------
__global__ __launch_bounds__(256) void k_pool1(const ushort_t* __restrict__ V,
                                               const int* __restrict__ batch,
                                               float* __restrict__ partial) {
    const int g = blockIdx.x / PSPLIT;
    const int s = blockIdx.x % PSPLIT;
    int beg, end;
    {
        int lo = 0, hi = NN;
        while (lo < hi) { int mid = (lo + hi) >> 1; if (batch[mid] < g) lo = mid + 1; else hi = mid; }
        beg = lo;
        lo = beg; hi = NN;
        while (lo < hi) { int mid = (lo + hi) >> 1; if (batch[mid] < g + 1) lo = mid + 1; else hi = mid; }
        end = lo;
    }
    const int c = threadIdx.x & 15;    // uint2 group = 4 channels (64 ch = 16 groups)
    const int rg = threadIdx.x >> 4;   // 0..15 node subgroup
    const uint2* __restrict__ V2 = (const uint2*)V;

    float4 acc = make_float4(0.f, 0.f, 0.f, 0.f);
    for (int n = beg + s * 16 + rg; n < end; n += PSPLIT * 16) {
        uint2 h = V2[(long)n * 16 + c];
        acc.x += bf_lo(h.x); acc.y += bf_hi(h.x);
        acc.z += bf_lo(h.y); acc.w += bf_hi(h.y);
    }
    __shared__ float4 red[16][17];
    red[rg][c] = acc;
    __syncthreads();
    if (rg == 0) {
        float4 t = red[0][c];
#pragma unroll
        for (int i = 1; i < 16; ++i) {
            float4 u = red[i][c];
            t.x += u.x; t.y += u.y; t.z += u.z; t.w += u.w;
        }
        ((float4*)partial)[(long)blockIdx.x * 16 + c] = t;
    }
}

__global__ __launch_bounds__(64) void k_pool2(const float* __restrict__ partial,
                                              const int* __restrict__ batch,
                                              const float* __restrict__ b2,
                                              float* __restrict__ out) {
    const int g = blockIdx.x;
    const int ch = threadIdx.x;
    int beg, end;
    {
        int lo = 0, hi = NN;
        while (lo < hi) { int mid = (lo + hi) >> 1; if (batch[mid] < g) lo = mid + 1; else hi = mid; }
        beg = lo;
        lo = beg; hi = NN;
        while (lo < hi) { int mid = (lo + hi) >> 1; if (batch[mid] < g + 1) lo = mid + 1; else hi = mid; }
        end = lo;
    }
    float s = 0.f;
    for (int i = 0; i < PSPLIT; ++i) s += partial[(long)(g * PSPLIT + i) * 64 + ch];
    int cnt = end - beg;
    out[g * 64 + ch] = (cnt > 0) ? (s / (float)cnt + b2[ch]) : 0.f;
}

extern "C" void kernel_launch(void* const* d_in, const int* in_sizes, int n_in,
                              void* d_out, int out_size, void* d_ws, size_t ws_size,
                              hipStream_t stream) {
    const float* x  = (const float*)d_in[0];
    const float* W1 = (const float*)d_in[1];
    const float* b1 = (const float*)d_in[2];
    const float* W2 = (const float*)d_in[3];
    const float* b2 = (const float*)d_in[4];
    const int* ei   = (const int*)d_in[5];
    const int* src  = ei;
    const int* dst  = ei + NE;
    const int* batch = (const int*)d_in[6];
    float* out = (float*)d_out;

    char* p = (char*)d_ws;
    int* deg       = (int*)p;          p += (size_t)NN * 4;
    int* rowptr    = (int*)p;          p += (size_t)(NN + 4) * 4;
    int* cursor    = (int*)p;          p += (size_t)NN * 4;
    int* csr_src   = (int*)p;          p += (size_t)NE * 4;
    int* blockSums = (int*)p;          p += (size_t)64 * 4;
    float* dinv    = (float*)p;        p += (size_t)NN * 4;
    float* partial = (float*)p;        p += (size_t)NG * PSPLIT * 64 * 4;
    ushort_t* W1t  = (ushort_t*)p;     p += (size_t)128 * 128 * 2;  // bf16 W1^T
    ushort_t* W2t  = (ushort_t*)p;     p += (size_t)64 * 128 * 2;   // bf16 W2^T
    ushort_t* Hb   = (ushort_t*)p;     p += (size_t)NN * 128 * 2;   // bf16 gemm1 out (pre-scaled)
    ushort_t* H1b  = (ushort_t*)p;     p += (size_t)NN * 128 * 2;   // bf16 h1 = relu(agg1+b1)
    ushort_t* Gb   = (ushort_t*)p;     p += (size_t)NN * 64 * 2;    // bf16 gemm2 out (pre-scaled)
    ushort_t* Vb   = (ushort_t*)p;     p += (size_t)NN * 64 * 2;    // bf16 layer2 agg out

    // ---- CSR build + normalization + W prep ----
    k_wprep<<<96, 256, 0, stream>>>(W1, W2, W1t, W2t);
    k_zero_deg<<<(NN + 255) / 256, 256, 0, stream>>>(deg);
    k_hist<<<(NE + 255) / 256, 256, 0, stream>>>(dst, deg);
    k_scan1<<<SCAN_NB, SCAN_T, 0, stream>>>(deg, blockSums);
    k_scan3<<<SCAN_NB, SCAN_T, 0, stream>>>(deg, blockSums, rowptr, cursor, dinv);
    k_scatter<<<(NE + 255) / 256, 256, 0, stream>>>(src, dst, cursor, csr_src);

    // ---- layer 1: MFMA gemm + aggregate (+bias,relu) ----
    k_gemm_mfma<<<(NN + 127) / 128, 256, 0, stream>>>(x, W1t, dinv, Hb);
    k_agg<128, 0><<<(NN + 15) / 16, 256, 0, stream>>>(rowptr, csr_src, dinv, Hb, b1, H1b);

    // ---- layer 2: MFMA gemm (128->64) + aggregate ----
    k_gemm_mfma2<<<(NN + 127) / 128, 256, 0, stream>>>(H1b, W2t, dinv, Gb);
    k_agg<64, 1><<<(NN + 31) / 32, 256, 0, stream>>>(rowptr, csr_src, dinv, Gb, b1 /*unused*/, Vb);

    // ---- pool (64 ch bf16) + b2 ----
    k_pool1<<<NG * PSPLIT, 256, 0, stream>>>(Vb, batch, partial);
    k_pool2<<<NG, 64, 0, stream>>>(partial, batch, b2, out);
}